// Round 11
// baseline (66.099 us; speedup 1.0000x reference)
//
#include <hip/hip_runtime.h>
#include <math.h>

#define NEG_SLOPE 0.1f
#define LOG2E 1.4426950408889634f
#define GROUPS 512

typedef _Float16 half8  __attribute__((ext_vector_type(8)));
typedef _Float16 half4t __attribute__((ext_vector_type(4)));
typedef __fp16   pk16x2 __attribute__((ext_vector_type(2)));   // cvt_pkrtz return type
typedef float    f32x4  __attribute__((ext_vector_type(4)));

__device__ __forceinline__ f32x4 mfma_f16(half8 a, half8 b, f32x4 c) {
    return __builtin_amdgcn_mfma_f32_16x16x32_f16(a, b, c, 0, 0, 0);
}

// R11 = INSTRUMENTATION ROUND. Body = R10 exactly, executed TWICE per launch
// (identical passes, both write the same correct Out). Purpose: push dur_us
// above the harness's ~40us fillBuffer dispatches so OUR kernel finally
// appears in the rocprof top-5 with VGPR/Occupancy/VALUBusy/WRITE_SIZE.
// Real per-pass perf ~= dur_us / 2. Input pointers are laundered through an
// empty asm with a "memory" clobber each pass so the compiler cannot CSE
// pass-2's loads/compute against pass-1 (__restrict__ would otherwise allow
// it). End-of-body __syncthreads() isolates LDS lifetimes between passes.
__global__ __launch_bounds__(512, 2)
void egat_fused(const float* __restrict__ Hin,
                const float* __restrict__ Wm,
                const float* __restrict__ att,
                float* __restrict__ Out)
{
    const int g    = blockIdx.x;
    const int tid  = threadIdx.x;
    const int w    = tid >> 6;    // 0..7
    const int lane = tid & 63;
    const int lg   = lane >> 4;   // 0..3
    const int lc   = lane & 15;   // 0..15

    __shared__ __align__(16) _Float16 fragV[8 * 4 * 64 * 8];   // 32 KB Wh B-frags [ktv][ot][lane][e]
    __shared__ __align__(16) _Float16 WtF[2 * 4 * 64 * 8];     // 8 KB f16 W^T B-frags
    __shared__ __align__(16) float u_lds[128];                 // u_s[64] | u_t[64]
    __shared__ __align__(16) float s_lds[256];
    __shared__ __align__(16) float t_lds[256];

    #pragma unroll 1
    for (int pass = 0; pass < 2; ++pass) {
        // launder pointers: forces pass 2 to redo loads + compute
        const float* Hp = Hin;
        const float* Wp = Wm;
        const float* ap = att;
        asm volatile("" : "+v"(Hp), "+v"(Wp), "+v"(ap) :: "memory");

        // ---------- phase A: h loads -> A-frags; u; Wt frags ----------
        half8 Ahi[2][2], Alo[2][2];   // [it][kt]; A-row = 32w + 16it + lc
        {
            const float* hbase = Hp + (size_t)(g * 256 + w * 32) * 64;
            #pragma unroll
            for (int it = 0; it < 2; ++it) {
                const float* rp = hbase + (it * 16 + lc) * 64 + lg * 8;
                #pragma unroll
                for (int kt = 0; kt < 2; ++kt) {
                    f32x4 f0 = *(const f32x4*)(rp + kt * 32);
                    f32x4 f1 = *(const f32x4*)(rp + kt * 32 + 4);
                    half8 hi, lo;
                    #pragma unroll
                    for (int e = 0; e < 4; ++e) {
                        _Float16 a0 = (_Float16)f0[e], a1 = (_Float16)f1[e];
                        hi[e]     = a0;  lo[e]     = (_Float16)(f0[e] - (float)a0);
                        hi[e + 4] = a1;  lo[e + 4] = (_Float16)(f1[e] - (float)a1);
                    }
                    Ahi[it][kt] = hi;
                    Alo[it][kt] = lo;
                }
            }
        }
        const float ae = ap[128];

        // wave 0: u_s = W^T a_src, u_t = W^T a_dst
        if (w == 0) {
            float us = 0.f, ut = 0.f;
            #pragma unroll 16
            for (int o = 0; o < 64; ++o) {
                float wv = Wp[o * 64 + lane];
                us = fmaf(wv, ap[o], us);
                ut = fmaf(wv, ap[64 + o], ut);
            }
            u_lds[lane]      = us;
            u_lds[64 + lane] = ut;
        }

        // W^T B-frags, single f16; 512 frag rows, one per thread
        {
            const int fr = tid;
            const int ln = fr & 63;
            const int ot = (fr >> 6) & 3;
            const int kt = fr >> 8;
            const float* wp = Wp + (ot * 16 + (ln & 15)) * 64 + kt * 32 + (ln >> 4) * 8;
            half8 hi;
            #pragma unroll
            for (int e = 0; e < 8; ++e) hi[e] = (_Float16)wp[e];
            *(half8*)&WtF[fr * 8] = hi;
        }
        __syncthreads();   // barrier 1: Wt frags + u ready

        // ---------- phase B: GEMM1  [Wh | s | t] ----------
        half8 Shi[2], Slo[2];   // st-tile B-frags (cols 0=u_s, 1=u_t), hi/lo
        #pragma unroll
        for (int kt = 0; kt < 2; ++kt) {
            if (lc < 2) {
                const float* up = &u_lds[lc * 64 + kt * 32 + lg * 8];
                f32x4 a = *(const f32x4*)up;
                f32x4 b2 = *(const f32x4*)(up + 4);
                #pragma unroll
                for (int e = 0; e < 4; ++e) {
                    _Float16 h0 = (_Float16)a[e], h1 = (_Float16)b2[e];
                    Shi[kt][e]     = h0;  Slo[kt][e]     = (_Float16)(a[e] - (float)h0);
                    Shi[kt][e + 4] = h1;  Slo[kt][e + 4] = (_Float16)(b2[e] - (float)h1);
                }
            } else {
                #pragma unroll
                for (int e = 0; e < 8; ++e) { Shi[kt][e] = (_Float16)0.f; Slo[kt][e] = (_Float16)0.f; }
            }
        }

        f32x4 acc[2][5];   // [it][ot 0..3 = Wh cols, 4 = [s|t] tile]
        #pragma unroll
        for (int it = 0; it < 2; ++it)
            #pragma unroll
            for (int ot = 0; ot < 5; ++ot)
                acc[it][ot] = f32x4{0.f, 0.f, 0.f, 0.f};

        #pragma unroll
        for (int kt = 0; kt < 2; ++kt) {
            #pragma unroll
            for (int ot = 0; ot < 4; ++ot) {
                half8 bh = *(half8*)&WtF[((kt * 4 + ot) * 64 + lane) * 8];
                #pragma unroll
                for (int it = 0; it < 2; ++it)
                    acc[it][ot] = mfma_f16(Ahi[it][kt], bh, acc[it][ot]);   // V: single f16
            }
            #pragma unroll
            for (int it = 0; it < 2; ++it) {                                 // s,t: hi/lo exact
                acc[it][4] = mfma_f16(Ahi[it][kt], Shi[kt], acc[it][4]);
                acc[it][4] = mfma_f16(Ahi[it][kt], Slo[kt], acc[it][4]);
                acc[it][4] = mfma_f16(Alo[it][kt], Shi[kt], acc[it][4]);
            }
        }

        // s,t to LDS (pre-scaled by log2 e; ae folded into s). C/D row = 32w+16it+4lg+r.
        #pragma unroll
        for (int it = 0; it < 2; ++it) {
            #pragma unroll
            for (int r = 0; r < 4; ++r) {
                int row = w * 32 + it * 16 + lg * 4 + r;
                float v = acc[it][4][r];
                if (lc == 0)      s_lds[row] = (v + ae) * LOG2E;
                else if (lc == 1) t_lds[row] = v * LOG2E;
            }
        }

        // scatter Wh (f16) into B-frag-packed fragV.
        // Row R = 32w+16it+4lg+r: ktv=w, lane2=(2it+(lg>>1))*16+lc, e=4(lg&1)+r
        #pragma unroll
        for (int it = 0; it < 2; ++it) {
            const int lane2 = (2 * it + (lg >> 1)) * 16 + lc;
            const int eb    = (lg & 1) * 4;
            #pragma unroll
            for (int ot = 0; ot < 4; ++ot) {
                half4t v;
                #pragma unroll
                for (int r = 0; r < 4; ++r) v[r] = (_Float16)acc[it][ot][r];
                *(half4t*)&fragV[((w * 4 + ot) * 64 + lane2) * 8 + eb] = v;
            }
        }
        __syncthreads();   // barrier 2: fragV + s,t ready

        // ---------- phase C: P in A-frag registers + GEMM2 (+ ones-tile denom) ----------
        float sa[2];
        #pragma unroll
        for (int it = 0; it < 2; ++it)
            sa[it] = s_lds[w * 32 + it * 16 + lc];   // A-row = 32w+16it+lc

        half8 ones;
        #pragma unroll
        for (int e = 0; e < 8; ++e) ones[e] = (_Float16)1.f;

        f32x4 acc2[2][5];   // [it][ot 0..3 = out cols, 4 = row-sum l]
        #pragma unroll
        for (int it = 0; it < 2; ++it)
            #pragma unroll
            for (int ot = 0; ot < 5; ++ot)
                acc2[it][ot] = f32x4{0.f, 0.f, 0.f, 0.f};

        for (int ktv = 0; ktv < 8; ++ktv) {
            f32x4 t0 = *(const f32x4*)&t_lds[ktv * 32 + lg * 8];
            f32x4 t1 = *(const f32x4*)&t_lds[ktv * 32 + lg * 8 + 4];
            half8 bfr[4];
            #pragma unroll
            for (int ot = 0; ot < 4; ++ot)
                bfr[ot] = *(half8*)&fragV[((ktv * 4 + ot) * 64 + lane) * 8];

            #pragma unroll
            for (int it = 0; it < 2; ++it) {
                float p[8];
                #pragma unroll
                for (int e = 0; e < 8; ++e) {
                    float z = sa[it] + (e < 4 ? t0[e] : t1[e - 4]);   // already *log2e
                    float x = fmaxf(z, NEG_SLOPE * z);                // leaky_relu
                    p[e] = __builtin_amdgcn_exp2f(x);                 // native v_exp_f32
                }
                union { pk16x2 h2[4]; half8 h8; } pk;
                #pragma unroll
                for (int e = 0; e < 4; ++e)
                    pk.h2[e] = __builtin_amdgcn_cvt_pkrtz(p[2 * e], p[2 * e + 1]);

                acc2[it][4] = mfma_f16(pk.h8, ones, acc2[it][4]);     // l_row in every lane
                #pragma unroll
                for (int ot = 0; ot < 4; ++ot)
                    acc2[it][ot] = mfma_f16(pk.h8, bfr[ot], acc2[it][ot]);
            }
        }

        // ---------- epilogue: scale by 1/l, store ----------
        const size_t orow0 = (size_t)(g * 256 + w * 32) * 64;
        #pragma unroll
        for (int it = 0; it < 2; ++it) {
            #pragma unroll
            for (int r = 0; r < 4; ++r) {
                float inv = __builtin_amdgcn_rcpf(acc2[it][4][r]);
                float* op = Out + orow0 + (size_t)(it * 16 + lg * 4 + r) * 64 + lc;
                #pragma unroll
                for (int ot = 0; ot < 4; ++ot)
                    op[ot * 16] = acc2[it][ot][r] * inv;
            }
        }
        __syncthreads();   // isolate LDS lifetimes between passes
    }
}

extern "C" void kernel_launch(void* const* d_in, const int* in_sizes, int n_in,
                              void* d_out, int out_size, void* d_ws, size_t ws_size,
                              hipStream_t stream) {
    const float* h   = (const float*)d_in[0];
    // d_in[1] = ind_id: regular 256-per-group structure; unused.
    const float* W   = (const float*)d_in[2];
    const float* att = (const float*)d_in[3];
    float* out = (float*)d_out;
    egat_fused<<<dim3(GROUPS), dim3(512), 0, stream>>>(h, W, att, out);
}

// Round 12
// 24.581 us; speedup vs baseline: 2.6890x; 2.6890x over previous
//
#include <hip/hip_runtime.h>
#include <math.h>

#define NEG_SLOPE 0.1f
#define LOG2E 1.4426950408889634f
#define GROUPS 512

typedef _Float16 half8  __attribute__((ext_vector_type(8)));
typedef _Float16 half4t __attribute__((ext_vector_type(4)));
typedef __fp16   pk16x2 __attribute__((ext_vector_type(2)));   // cvt_pkrtz return type
typedef float    f32x4  __attribute__((ext_vector_type(4)));

__device__ __forceinline__ f32x4 mfma_f16(half8 a, half8 b, f32x4 c) {
    return __builtin_amdgcn_mfma_f32_16x16x32_f16(a, b, c, 0, 0, 0);
}

// R12: persistent-block pipeline. 256 blocks x 1024 thr (16 waves = 4/SIMD,
// exactly 1 block/CU); block b owns groups 2b and 2b+1, processed
// sequentially with software pipelining:
//   - h loads for BOTH groups issued in the prologue (raw f32 held in 32
//     VGPRs) -> HBM streams while group 0 computes; latency fully covered.
//   - fragV / s / t double-buffered (76.5 KB LDS, 1 block/CU anyway) -> no
//     WAR barrier between g0's GEMM2 reads and g1's scatter writes; waves
//     drift freely between store-g0 and GEMM1-g1. 3 barriers total.
//   - W-prep (u, WtF, st-tile frags) hoisted out of the group loop.
// R11 counters that motivated this: VGPR=84 (no spill), MfmaUtil 7.7%,
// VALUBusy 20.5%, Occupancy 19.7% ~= ONE 512-thr block/CU -> convoy/latency
// bound. NOTE __launch_bounds__ 2nd arg is waves/EU: (512,2) = 1 block/CU —
// the R10 "2 co-resident blocks" premise was false. A 1024-thr block forces
// the compiler to fit 4 waves/SIMD (VGPR<=128) by itself.
//
// Validated algebra carried: s,t as 5th B-tile of GEMM1 (u_s=W^T a_src,
// u_t=W^T a_dst), softmax denom as all-ones 6th tile (l lands per-lane, no
// epilogue shuffles), native exp2 (exp2f is a libm call without -ffast-math),
// single-f16 V tile (err ~1e-3 << 1.56e-2 budget), hi/lo split for s,t only.
//
// MFMA 16x16x32_f16 layouts (m89-verified):
//   A: row = lane&15, k = 8*(lane>>4)+e (+32*kt)
//   B: col = lane&15 (+16*ot), k = 8*(lane>>4)+e (+32*kt)
//   C/D: col = lane&15 (+16*ot), row = 4*(lane>>4)+r
__global__ __launch_bounds__(1024)
void egat_fused(const float* __restrict__ Hin,
                const float* __restrict__ Wm,
                const float* __restrict__ att,
                float* __restrict__ Out)
{
    const int tid  = threadIdx.x;
    const int w    = tid >> 6;    // 0..15
    const int lane = tid & 63;
    const int lg   = lane >> 4;   // 0..3
    const int lc   = lane & 15;   // 0..15
    const int g0   = blockIdx.x * 2;

    __shared__ __align__(16) _Float16 fragV[2][8 * 4 * 64 * 8];  // 2 x 32 KB Wh B-frags
    __shared__ __align__(16) _Float16 WtF[2 * 4 * 64 * 8];       // 8 KB f16 W^T B-frags
    __shared__ __align__(16) float u_lds[128];                   // u_s[64] | u_t[64]
    __shared__ __align__(16) float s_lds[2][256];
    __shared__ __align__(16) float t_lds[2][256];

    // ---------- prologue: issue h loads for BOTH groups ----------
    f32x4 hraw[2][4];   // [grp][kt*2 + half]; row = 16w+lc, cols lg*8(+4) +32kt
    #pragma unroll
    for (int p = 0; p < 2; ++p) {
        const float* rp = Hin + (size_t)((g0 + p) * 256 + w * 16 + lc) * 64 + lg * 8;
        #pragma unroll
        for (int kt = 0; kt < 2; ++kt) {
            hraw[p][kt * 2]     = *(const f32x4*)(rp + kt * 32);
            hraw[p][kt * 2 + 1] = *(const f32x4*)(rp + kt * 32 + 4);
        }
    }
    const float ae = att[128];

    // wave 0: u_s = W^T a_src, u_t = W^T a_dst
    if (w == 0) {
        float us = 0.f, ut = 0.f;
        #pragma unroll 16
        for (int o = 0; o < 64; ++o) {
            float wv = Wm[o * 64 + lane];
            us = fmaf(wv, att[o], us);
            ut = fmaf(wv, att[64 + o], ut);
        }
        u_lds[lane]      = us;
        u_lds[64 + lane] = ut;
    }

    // W^T B-frags, single f16; 512 frag rows, threads 0..511 one each
    if (tid < 512) {
        const int fr = tid;
        const int ln = fr & 63;
        const int ot = (fr >> 6) & 3;
        const int kt = fr >> 8;
        const float* wp = Wm + (ot * 16 + (ln & 15)) * 64 + kt * 32 + (ln >> 4) * 8;
        half8 hi;
        #pragma unroll
        for (int e = 0; e < 8; ++e) hi[e] = (_Float16)wp[e];
        *(half8*)&WtF[fr * 8] = hi;
    }
    __syncthreads();   // barrier A: W frags + u ready

    // st-tile B-frags (cols 0=u_s, 1=u_t), hi/lo — once, W-only
    half8 Shi[2], Slo[2];
    #pragma unroll
    for (int kt = 0; kt < 2; ++kt) {
        if (lc < 2) {
            const float* up = &u_lds[lc * 64 + kt * 32 + lg * 8];
            f32x4 a = *(const f32x4*)up;
            f32x4 b2 = *(const f32x4*)(up + 4);
            #pragma unroll
            for (int e = 0; e < 4; ++e) {
                _Float16 h0 = (_Float16)a[e], h1 = (_Float16)b2[e];
                Shi[kt][e]     = h0;  Slo[kt][e]     = (_Float16)(a[e] - (float)h0);
                Shi[kt][e + 4] = h1;  Slo[kt][e + 4] = (_Float16)(b2[e] - (float)h1);
            }
        } else {
            #pragma unroll
            for (int e = 0; e < 8; ++e) { Shi[kt][e] = (_Float16)0.f; Slo[kt][e] = (_Float16)0.f; }
        }
    }

    half8 ones;
    #pragma unroll
    for (int e = 0; e < 8; ++e) ones[e] = (_Float16)1.f;

    // ---------- group loop (fully unrolled: all indices static) ----------
    #pragma unroll
    for (int p = 0; p < 2; ++p) {
        // convert raw h -> A-frags (hi/lo)
        half8 Ahi[2], Alo[2];
        #pragma unroll
        for (int kt = 0; kt < 2; ++kt) {
            f32x4 f0 = hraw[p][kt * 2], f1 = hraw[p][kt * 2 + 1];
            half8 hi, lo;
            #pragma unroll
            for (int e = 0; e < 4; ++e) {
                _Float16 a0 = (_Float16)f0[e], a1 = (_Float16)f1[e];
                hi[e]     = a0;  lo[e]     = (_Float16)(f0[e] - (float)a0);
                hi[e + 4] = a1;  lo[e + 4] = (_Float16)(f1[e] - (float)a1);
            }
            Ahi[kt] = hi;
            Alo[kt] = lo;
        }

        // GEMM1: [Wh | s | t]
        f32x4 acc[5];
        #pragma unroll
        for (int ot = 0; ot < 5; ++ot) acc[ot] = f32x4{0.f, 0.f, 0.f, 0.f};
        #pragma unroll
        for (int kt = 0; kt < 2; ++kt) {
            #pragma unroll
            for (int ot = 0; ot < 4; ++ot) {
                half8 bh = *(half8*)&WtF[((kt * 4 + ot) * 64 + lane) * 8];
                acc[ot] = mfma_f16(Ahi[kt], bh, acc[ot]);          // V: single f16
            }
            acc[4] = mfma_f16(Ahi[kt], Shi[kt], acc[4]);           // s,t: hi/lo exact
            acc[4] = mfma_f16(Ahi[kt], Slo[kt], acc[4]);
            acc[4] = mfma_f16(Alo[kt], Shi[kt], acc[4]);
        }

        // s,t to LDS (pre-scaled by log2 e; ae folded into s). C/D row = 16w+4lg+r.
        #pragma unroll
        for (int r = 0; r < 4; ++r) {
            int row = w * 16 + lg * 4 + r;
            float v = acc[4][r];
            if (lc == 0)      s_lds[p][row] = (v + ae) * LOG2E;
            else if (lc == 1) t_lds[p][row] = v * LOG2E;
        }

        // scatter Wh (f16) -> fragV[p].
        // Row R = 16w+4lg+r: ktv=w>>1, lane2=(2(w&1)+(lg>>1))*16+lc, e=4(lg&1)+r
        {
            const int ktv   = w >> 1;
            const int lane2 = (2 * (w & 1) + (lg >> 1)) * 16 + lc;
            const int eb    = (lg & 1) * 4;
            #pragma unroll
            for (int ot = 0; ot < 4; ++ot) {
                half4t v;
                #pragma unroll
                for (int r = 0; r < 4; ++r) v[r] = (_Float16)acc[ot][r];
                *(half4t*)&fragV[p][((ktv * 4 + ot) * 64 + lane2) * 8 + eb] = v;
            }
        }
        __syncthreads();   // barrier B_p: fragV[p] + s,t[p] ready

        // GEMM2: P in A-frag registers (+ ones-tile denominator)
        const float sa = s_lds[p][w * 16 + lc];   // A-row = 16w + lc

        f32x4 acc2[5];
        #pragma unroll
        for (int ot = 0; ot < 5; ++ot) acc2[ot] = f32x4{0.f, 0.f, 0.f, 0.f};

        for (int ktv = 0; ktv < 8; ++ktv) {
            f32x4 t0 = *(const f32x4*)&t_lds[p][ktv * 32 + lg * 8];
            f32x4 t1 = *(const f32x4*)&t_lds[p][ktv * 32 + lg * 8 + 4];

            float pr[8];
            #pragma unroll
            for (int e = 0; e < 8; ++e) {
                float z = sa + (e < 4 ? t0[e] : t1[e - 4]);   // already *log2e
                float x = fmaxf(z, NEG_SLOPE * z);            // leaky_relu
                pr[e] = __builtin_amdgcn_exp2f(x);            // native v_exp_f32
            }
            union { pk16x2 h2[4]; half8 h8; } pk;
            #pragma unroll
            for (int e = 0; e < 4; ++e)
                pk.h2[e] = __builtin_amdgcn_cvt_pkrtz(pr[2 * e], pr[2 * e + 1]);

            acc2[4] = mfma_f16(pk.h8, ones, acc2[4]);         // l_row in every lane
            #pragma unroll
            for (int ot = 0; ot < 4; ++ot) {
                half8 bfr = *(half8*)&fragV[p][((ktv * 4 + ot) * 64 + lane) * 8];
                acc2[ot] = mfma_f16(pk.h8, bfr, acc2[ot]);
            }
        }

        // store (no trailing barrier: waves drift into next group's GEMM1)
        const size_t orow0 = (size_t)((g0 + p) * 256 + w * 16) * 64;
        #pragma unroll
        for (int r = 0; r < 4; ++r) {
            float inv = __builtin_amdgcn_rcpf(acc2[4][r]);
            float* op = Out + orow0 + (size_t)(lg * 4 + r) * 64 + lc;
            #pragma unroll
            for (int ot = 0; ot < 4; ++ot)
                op[ot * 16] = acc2[ot][r] * inv;
        }
    }
}

extern "C" void kernel_launch(void* const* d_in, const int* in_sizes, int n_in,
                              void* d_out, int out_size, void* d_ws, size_t ws_size,
                              hipStream_t stream) {
    const float* h   = (const float*)d_in[0];
    // d_in[1] = ind_id: regular 256-per-group structure; unused.
    const float* W   = (const float*)d_in[2];
    const float* att = (const float*)d_in[3];
    float* out = (float*)d_out;
    egat_fused<<<dim3(GROUPS / 2), dim3(1024), 0, stream>>>(h, W, att, out);
}